// Round 10
// baseline (185.958 us; speedup 1.0000x reference)
//
#include <hip/hip_runtime.h>
#include <hip/hip_bf16.h>
#include <math.h>

// Problem constants (from reference)
constexpr int B  = 8;
constexpr int S  = 2048;
constexpr int H  = 4096;
constexpr int NSLOT = 64;
constexpr int MEM = 16;
constexpr int RH = 256;
constexpr int H4 = H / 4;         // 1024 float4 per row
constexpr int SCHUNK = 16;        // split of S for the mean reduction

typedef float fx4 __attribute__((ext_vector_type(4)));

__device__ __forceinline__ float4 ntload4(const float4* p) {
    fx4 v = __builtin_nontemporal_load(reinterpret_cast<const fx4*>(p));
    return make_float4(v.x, v.y, v.z, v.w);
}
__device__ __forceinline__ void ntstore4(float4* p, float4 v) {
    fx4 w = {v.x, v.y, v.z, v.w};
    __builtin_nontemporal_store(w, reinterpret_cast<fx4*>(p));
}

// ---------------------------------------------------------------------------
// K1: partial column sums of embeds over S-chunks. 512 blocks x 256 thr.
// (round-4 proven; NT loads, fully co-resident)
// ---------------------------------------------------------------------------
__global__ __launch_bounds__(256) void k_partial(const float* __restrict__ embeds,
                                                 float* __restrict__ partial) {
    int blk = blockIdx.x;
    int c   = blk % SCHUNK;
    int ht  = (blk / SCHUNK) % (H4 / 256);
    int b   = blk / (SCHUNK * (H4 / 256));
    int h4  = ht * 256 + threadIdx.x;

    const float4* src = (const float4*)embeds + (size_t)b * S * H4 + h4;
    int s0 = c * (S / SCHUNK);
    float4 acc = {0.f, 0.f, 0.f, 0.f};
    #pragma unroll 8
    for (int s = 0; s < S / SCHUNK; ++s) {
        float4 v = ntload4(&src[(size_t)(s0 + s) * H4]);
        acc.x += v.x; acc.y += v.y; acc.z += v.z; acc.w += v.w;
    }
    ((float4*)partial)[((size_t)b * SCHUNK + c) * H4 + h4] = acc;
}

// ---------------------------------------------------------------------------
// K2: finish mean. 32 blocks x 256 threads. (round-4 proven)
// ---------------------------------------------------------------------------
__global__ __launch_bounds__(256) void k_mean(const float* __restrict__ partial,
                                              float* __restrict__ q) {
    int i  = blockIdx.x * 256 + threadIdx.x;
    int b  = i / H4;
    int h4 = i % H4;
    const float4* p4 = (const float4*)partial;
    float4 acc = {0.f, 0.f, 0.f, 0.f};
    #pragma unroll
    for (int c = 0; c < SCHUNK; ++c) {
        float4 v = p4[((size_t)b * SCHUNK + c) * H4 + h4];
        acc.x += v.x; acc.y += v.y; acc.z += v.z; acc.w += v.w;
    }
    const float inv = 1.0f / (float)S;
    acc.x *= inv; acc.y *= inv; acc.z *= inv; acc.w *= inv;
    ((float4*)q)[i] = acc;
}

// ---------------------------------------------------------------------------
// K3: h[b][r] = relu(W1[r] . q[b] + b1[r]). 256 blocks. (round-4 proven)
// ---------------------------------------------------------------------------
__global__ __launch_bounds__(256) void k_w1(const float* __restrict__ q,
                                            const float* __restrict__ W1,
                                            const float* __restrict__ b1,
                                            float* __restrict__ hws) {
    __shared__ float wred[4][B];
    int r = blockIdx.x, t = threadIdx.x;
    const float4* w4 = (const float4*)W1 + (size_t)r * H4;
    const float4* q4 = (const float4*)q;

    float acc[B];
    #pragma unroll
    for (int b = 0; b < B; ++b) acc[b] = 0.f;

    #pragma unroll
    for (int i = 0; i < H4 / 256; ++i) {
        int idx = i * 256 + t;
        float4 wv = ntload4(&w4[idx]);
        #pragma unroll
        for (int b = 0; b < B; ++b) {
            float4 qv = q4[(size_t)b * H4 + idx];
            acc[b] += wv.x * qv.x + wv.y * qv.y + wv.z * qv.z + wv.w * qv.w;
        }
    }
    #pragma unroll
    for (int b = 0; b < B; ++b) {
        float v = acc[b];
        #pragma unroll
        for (int off = 32; off > 0; off >>= 1) v += __shfl_down(v, off, 64);
        acc[b] = v;
    }
    int wave = t >> 6, lane = t & 63;
    if (lane == 0) {
        #pragma unroll
        for (int b = 0; b < B; ++b) wred[wave][b] = acc[b];
    }
    __syncthreads();
    if (t < B) {
        float s2 = wred[0][t] + wred[1][t] + wred[2][t] + wred[3][t] + b1[r];
        hws[(size_t)t * RH + r] = fmaxf(s2, 0.0f);
    }
}

// ---------------------------------------------------------------------------
// K4: routing (logits + wave top-k + softmax + sigmoid fold) + contrib, ONCE.
// 32 blocks x 256 thr: b = blk>>2, ht = blk&3. (round-4 proven)
// ---------------------------------------------------------------------------
__global__ __launch_bounds__(256) void k_gc(const float* __restrict__ hws,
                                            const float* __restrict__ W2,
                                            const float* __restrict__ b2,
                                            const float* __restrict__ gate,
                                            const float* __restrict__ memory,
                                            const int* __restrict__ topk_p,
                                            float* __restrict__ contrib) {
    __shared__ float lh[RH];
    __shared__ float wf[128];     // [k][m], k<8
    int blk = blockIdx.x;
    int b   = blk >> 2;
    int ht  = blk & 3;
    int t   = threadIdx.x, lane = t & 63;

    int K = topk_p[0];
    if (K > 8) K = 8;
    if (K < 1) K = 1;

    if (t < 64) {
        float4 hv = ((const float4*)hws)[(size_t)b * (RH / 4) + t];
        lh[t * 4 + 0] = hv.x; lh[t * 4 + 1] = hv.y;
        lh[t * 4 + 2] = hv.z; lh[t * 4 + 3] = hv.w;
    }
    __syncthreads();

    // logits: lane n owns slot n (all 4 waves compute redundantly)
    float logit;
    {
        const float4* w4 = (const float4*)W2 + (size_t)lane * (RH / 4);
        float acc = b2[lane];
        #pragma unroll 8
        for (int i = 0; i < RH / 4; ++i) {
            float4 wv = w4[i];
            acc += wv.x * lh[4 * i] + wv.y * lh[4 * i + 1] +
                   wv.z * lh[4 * i + 2] + wv.w * lh[4 * i + 3];
        }
        logit = acc;              // TEMP == 1.0
    }

    // wave-parallel top-8 (only k<K used); ties -> lowest index
    float v = logit;
    float tvals[8]; int tids[8];
    #pragma unroll
    for (int k = 0; k < 8; ++k) {
        float m = v; int mi = lane;
        #pragma unroll
        for (int off = 32; off > 0; off >>= 1) {
            float om = __shfl_xor(m, off, 64);
            int   oi = __shfl_xor(mi, off, 64);
            if (om > m || (om == m && oi < mi)) { m = om; mi = oi; }
        }
        tvals[k] = m; tids[k] = mi;
        if (lane == mi) v = -INFINITY;
    }

    // softmax over selected logits (uniform across lanes)
    float mx = tvals[0];
    float e[8]; float se = 0.f;
    #pragma unroll
    for (int k = 0; k < 8; ++k) {
        float ek = (k < K) ? expf(tvals[k] - mx) : 0.f;
        e[k] = ek; se += ek;
    }
    float inv = 1.0f / se;

    // fold: wf[k][m] = softmax_k * sigmoid(gate[slot_k][m]); threads 0..127
    if (t < 128) {
        int k_of = t >> 4, m_of = t & 15;
        float wfv = 0.f;
        #pragma unroll
        for (int k = 0; k < 8; ++k) {
            if (k < K && k == k_of) {
                float g = gate[tids[k] * MEM + m_of];
                wfv = e[k] * inv / (1.0f + expf(-g));
            }
        }
        wf[t] = wfv;
    }
    __syncthreads();

    // contrib slice: h4 = ht*256 + t
    int h4 = ht * 256 + t;
    float4 a = {0.f, 0.f, 0.f, 0.f};
    #pragma unroll
    for (int k = 0; k < 8; ++k) {
        if (k < K) {
            const float4* mp = (const float4*)memory + ((size_t)tids[k] * MEM) * H4 + h4;
            #pragma unroll
            for (int m = 0; m < MEM; ++m) {
                float w = wf[k * MEM + m];
                float4 vv = mp[(size_t)m * H4];
                a.x += w * vv.x; a.y += w * vv.y; a.z += w * vv.z; a.w += w * vv.w;
            }
        }
    }
    ((float4*)contrib)[(size_t)b * H4 + h4] = a;
}

// ---------------------------------------------------------------------------
// K5: out = hidden + contrib[b][h4].  2048 blocks x 256 thr (8/CU, fully
// co-resident, no dispatch tail). Static 32-iteration loop:
//   i = tid + k*STRIDE, STRIDE = 2048*256 = 2^19; 2^19 % H4 == 0 -> h4 is
//   loop-invariant per thread; b = i >> 21 changes every 4 iters -> contrib
//   load hoisted to once per b.
// ---------------------------------------------------------------------------
__global__ __launch_bounds__(256) void k_add(const float* __restrict__ hidden,
                                             const float* __restrict__ contrib,
                                             float* __restrict__ out) {
    constexpr size_t STRIDE = (size_t)2048 * 256;        // 2^19
    const size_t tid = (size_t)blockIdx.x * 256 + threadIdx.x;
    const int h4 = (int)(tid & (size_t)(H4 - 1));        // loop-invariant
    const float4* hv4 = (const float4*)hidden;
    const float4* cv4 = (const float4*)contrib;
    float4* o4 = (float4*)out;

    #pragma unroll
    for (int bb = 0; bb < B; ++bb) {                     // b = i>>21 == bb
        float4 cv = cv4[(size_t)bb * H4 + h4];           // one L1/L2 hit per b
        #pragma unroll
        for (int j = 0; j < 4; ++j) {                    // 4 iters per b
            size_t i = tid + (size_t)(bb * 4 + j) * STRIDE;
            float4 hv = ntload4(&hv4[i]);
            float4 o  = {hv.x + cv.x, hv.y + cv.y, hv.z + cv.z, hv.w + cv.w};
            ntstore4(&o4[i], o);
        }
    }
}

// ---------------------------------------------------------------------------
extern "C" void kernel_launch(void* const* d_in, const int* in_sizes, int n_in,
                              void* d_out, int out_size, void* d_ws, size_t ws_size,
                              hipStream_t stream) {
    const float* embeds = (const float*)d_in[0];
    const float* hidden = (const float*)d_in[1];
    const float* W1     = (const float*)d_in[2];
    const float* b1     = (const float*)d_in[3];
    const float* W2     = (const float*)d_in[4];
    const float* b2     = (const float*)d_in[5];
    const float* gate   = (const float*)d_in[6];
    const float* memory = (const float*)d_in[7];
    const int*   topk   = (const int*)d_in[8];
    float* out = (float*)d_out;

    // workspace layout (floats)
    float* partial = (float*)d_ws;                        // B*SCHUNK*H = 524288
    float* q       = partial + (size_t)B * SCHUNK * H;    // B*H        = 32768
    float* hws     = q       + (size_t)B * H;             // B*RH       = 2048
    float* contrib = hws     + (size_t)B * RH;            // B*H        = 32768

    k_partial<<<dim3(B * (H4 / 256) * SCHUNK), dim3(256), 0, stream>>>(embeds, partial);
    k_mean   <<<dim3(B * H4 / 256),            dim3(256), 0, stream>>>(partial, q);
    k_w1     <<<dim3(RH),                      dim3(256), 0, stream>>>(q, W1, b1, hws);
    k_gc     <<<dim3(B * (H4 / 256)),          dim3(256), 0, stream>>>(hws, W2, b2, gate,
                                                                       memory, topk, contrib);
    k_add    <<<dim3(2048),                    dim3(256), 0, stream>>>(hidden, contrib, out);
}

// Round 11
// 161.269 us; speedup vs baseline: 1.1531x; 1.1531x over previous
//
#include <hip/hip_runtime.h>
#include <hip/hip_bf16.h>
#include <math.h>

// Problem constants (from reference)
constexpr int B  = 8;
constexpr int S  = 2048;
constexpr int H  = 4096;
constexpr int N  = 64;    // N_SLOTS
constexpr int MEM = 16;
constexpr int RH = 256;
constexpr int H4 = H / 4;         // 1024 float4 per row
constexpr int SCHUNK = 16;        // split of S for the mean reduction

typedef float fx4 __attribute__((ext_vector_type(4)));

__device__ __forceinline__ float4 ntload4(const float4* p) {
    fx4 v = __builtin_nontemporal_load(reinterpret_cast<const fx4*>(p));
    return make_float4(v.x, v.y, v.z, v.w);
}
__device__ __forceinline__ void ntstore4(float4* p, float4 v) {
    fx4 w = {v.x, v.y, v.z, v.w};
    __builtin_nontemporal_store(w, reinterpret_cast<fx4*>(p));
}

// ---------------------------------------------------------------------------
// K1: partial column sums of embeds over S-chunks.
// grid = B * (H4/256) * SCHUNK = 512 blocks, 256 threads. Deterministic.
// embeds is streamed exactly once -> nontemporal loads.
// ---------------------------------------------------------------------------
__global__ __launch_bounds__(256) void k_partial(const float* __restrict__ embeds,
                                                 float* __restrict__ partial) {
    int blk = blockIdx.x;
    int c   = blk % SCHUNK;                       // s-chunk
    int ht  = (blk / SCHUNK) % (H4 / 256);        // h-tile
    int b   = blk / (SCHUNK * (H4 / 256));        // batch
    int h4  = ht * 256 + threadIdx.x;

    const float4* src = (const float4*)embeds + (size_t)b * S * H4 + h4;
    int s0 = c * (S / SCHUNK);
    float4 acc = {0.f, 0.f, 0.f, 0.f};
    #pragma unroll 8
    for (int s = 0; s < S / SCHUNK; ++s) {
        float4 v = ntload4(&src[(size_t)(s0 + s) * H4]);
        acc.x += v.x; acc.y += v.y; acc.z += v.z; acc.w += v.w;
    }
    ((float4*)partial)[((size_t)b * SCHUNK + c) * H4 + h4] = acc;
}

// ---------------------------------------------------------------------------
// K2a: finish mean. grid = 32 blocks x 256 threads = 8192 = B*H4 exactly.
// ---------------------------------------------------------------------------
__global__ __launch_bounds__(256) void k_mean(const float* __restrict__ partial,
                                              float* __restrict__ q) {
    int i  = blockIdx.x * 256 + threadIdx.x;      // 0 .. B*H4-1
    int b  = i / H4;
    int h4 = i % H4;
    const float4* p4 = (const float4*)partial;
    float4 acc = {0.f, 0.f, 0.f, 0.f};
    #pragma unroll
    for (int c = 0; c < SCHUNK; ++c) {
        float4 v = p4[((size_t)b * SCHUNK + c) * H4 + h4];
        acc.x += v.x; acc.y += v.y; acc.z += v.z; acc.w += v.w;
    }
    const float inv = 1.0f / (float)S;
    acc.x *= inv; acc.y *= inv; acc.z *= inv; acc.w *= inv;
    ((float4*)q)[i] = acc;
}

// ---------------------------------------------------------------------------
// K2b: h[b][r] = relu(W1[r] . q[b] + b1[r]).  grid = RH = 256 blocks.
// Each block reads its W1 row once, dots against all 8 batch queries.
// ---------------------------------------------------------------------------
__global__ __launch_bounds__(256) void k_w1(const float* __restrict__ q,
                                            const float* __restrict__ W1,
                                            const float* __restrict__ b1,
                                            float* __restrict__ hws) {
    __shared__ float wred[4][B];   // per-wave partials
    int r = blockIdx.x, t = threadIdx.x;
    const float4* w4 = (const float4*)W1 + (size_t)r * H4;
    const float4* q4 = (const float4*)q;

    float acc[B];
    #pragma unroll
    for (int b = 0; b < B; ++b) acc[b] = 0.f;

    #pragma unroll
    for (int i = 0; i < H4 / 256; ++i) {          // 4 iterations
        int idx = i * 256 + t;
        float4 wv = ntload4(&w4[idx]);            // W1 read exactly once globally
        #pragma unroll
        for (int b = 0; b < B; ++b) {
            float4 qv = q4[(size_t)b * H4 + idx];
            acc[b] += wv.x * qv.x + wv.y * qv.y + wv.z * qv.z + wv.w * qv.w;
        }
    }
    // wave-level reduce (wave64)
    #pragma unroll
    for (int b = 0; b < B; ++b) {
        float v = acc[b];
        #pragma unroll
        for (int off = 32; off > 0; off >>= 1) v += __shfl_down(v, off, 64);
        acc[b] = v;
    }
    int wave = t >> 6, lane = t & 63;
    if (lane == 0) {
        #pragma unroll
        for (int b = 0; b < B; ++b) wred[wave][b] = acc[b];
    }
    __syncthreads();
    if (t < B) {
        float s = wred[0][t] + wred[1][t] + wred[2][t] + wred[3][t] + b1[r];
        hws[(size_t)t * RH + r] = fmaxf(s, 0.0f);
    }
}

// ---------------------------------------------------------------------------
// K2c: fused gate (logits + wave-parallel top-k + softmax + sigmoid fold)
//      + contrib. grid = B * (H4/64) = 128 blocks, 64 threads (1 wave).
// Each block redundantly computes routing for its batch (cheap, parallel),
// then produces a 64-float4 slice of contrib.
// ---------------------------------------------------------------------------
__global__ __launch_bounds__(64) void k_gate_contrib(const float* __restrict__ hws,
                                                     const float* __restrict__ W2,
                                                     const float* __restrict__ b2,
                                                     const float* __restrict__ gate,
                                                     const float* __restrict__ memory,
                                                     const int* __restrict__ topk_p,
                                                     float* __restrict__ contrib) {
    __shared__ float lh[RH];      // hws row for this batch
    __shared__ float wf[64];      // folded weights: [k][m]

    int blk = blockIdx.x;
    int b   = blk / (H4 / 64);
    int ht  = blk % (H4 / 64);
    int lane = threadIdx.x;       // 0..63

    int K = topk_p[0];
    if (K > 8) K = 8;
    if (K < 1) K = 1;

    // stage hws[b][0..255] into LDS (64 lanes x float4)
    float4 hv = ((const float4*)hws)[(size_t)b * (RH / 4) + lane];
    lh[lane * 4 + 0] = hv.x; lh[lane * 4 + 1] = hv.y;
    lh[lane * 4 + 2] = hv.z; lh[lane * 4 + 3] = hv.w;
    __syncthreads();

    // logits: lane n owns slot n
    float logit;
    {
        const float4* w4 = (const float4*)W2 + (size_t)lane * (RH / 4);
        float acc = b2[lane];
        #pragma unroll 8
        for (int i = 0; i < RH / 4; ++i) {
            float4 wv = w4[i];
            acc += wv.x * lh[4 * i] + wv.y * lh[4 * i + 1] +
                   wv.z * lh[4 * i + 2] + wv.w * lh[4 * i + 3];
        }
        logit = acc;              // TEMP == 1.0
    }

    // wave-parallel top-8 (guarded by K at use sites); ties -> lowest index
    float v = logit;
    float tvals[8]; int tids[8];
    #pragma unroll
    for (int k = 0; k < 8; ++k) {
        float m = v; int mi = lane;
        #pragma unroll
        for (int off = 32; off > 0; off >>= 1) {
            float om = __shfl_xor(m, off, 64);
            int   oi = __shfl_xor(mi, off, 64);
            if (om > m || (om == m && oi < mi)) { m = om; mi = oi; }
        }
        tvals[k] = m; tids[k] = mi;
        if (lane == mi) v = -INFINITY;
    }

    // softmax over selected logits (uniform across lanes)
    float mx = tvals[0];
    float e[8]; float se = 0.f;
    #pragma unroll
    for (int k = 0; k < 8; ++k) {
        float ek = (k < K) ? expf(tvals[k] - mx) : 0.f;
        e[k] = ek; se += ek;
    }
    float inv = 1.0f / se;

    // fold: wf[k][m] = softmax_k * sigmoid(gate[slot_k][m]); lane = k*16+m
    {
        int k_of = lane >> 4, m_of = lane & 15;
        float wfv = 0.f;
        #pragma unroll
        for (int k = 0; k < 8; ++k) {
            if (k < K && k == k_of) {
                float g = gate[tids[k] * MEM + m_of];
                wfv = e[k] * inv / (1.0f + expf(-g));
            }
        }
        wf[lane] = wfv;
    }
    __syncthreads();

    // contrib slice: h4 = ht*64 + lane
    int h4 = ht * 64 + lane;
    float4 a = {0.f, 0.f, 0.f, 0.f};
    #pragma unroll
    for (int k = 0; k < 8; ++k) {
        if (k < K) {
            const float4* mp = (const float4*)memory + ((size_t)tids[k] * MEM) * H4 + h4;
            #pragma unroll
            for (int m = 0; m < MEM; ++m) {
                float w = wf[k * MEM + m];
                float4 vv = mp[(size_t)m * H4];
                a.x += w * vv.x; a.y += w * vv.y; a.z += w * vv.z; a.w += w * vv.w;
            }
        }
    }
    ((float4*)contrib)[(size_t)b * H4 + h4] = a;
}

// ---------------------------------------------------------------------------
// K3: out[b,s,h] = hidden[b,s,h] + contrib[b,h]   (float4 grid-stride)
// hidden/out streamed once -> nontemporal; contrib small -> cached.
// ---------------------------------------------------------------------------
__global__ __launch_bounds__(256) void k_add(const float* __restrict__ hidden,
                                             const float* __restrict__ contrib,
                                             float* __restrict__ out) {
    const size_t total4 = (size_t)B * S * H4;      // 16,777,216
    const size_t stride = (size_t)gridDim.x * blockDim.x;
    const float4* hv4 = (const float4*)hidden;
    const float4* cv4 = (const float4*)contrib;
    float4* o4 = (float4*)out;
    for (size_t i = (size_t)blockIdx.x * blockDim.x + threadIdx.x; i < total4; i += stride) {
        int h4 = (int)(i & (size_t)(H4 - 1));      // H4 = 1024 (pow2)
        int b  = (int)(i >> 21);                   // S*H4 = 2^21 per batch
        float4 hv = ntload4(&hv4[i]);
        float4 cv = cv4[(size_t)b * H4 + h4];
        float4 o  = {hv.x + cv.x, hv.y + cv.y, hv.z + cv.z, hv.w + cv.w};
        ntstore4(&o4[i], o);
    }
}

// ---------------------------------------------------------------------------
extern "C" void kernel_launch(void* const* d_in, const int* in_sizes, int n_in,
                              void* d_out, int out_size, void* d_ws, size_t ws_size,
                              hipStream_t stream) {
    const float* embeds = (const float*)d_in[0];
    const float* hidden = (const float*)d_in[1];
    const float* W1     = (const float*)d_in[2];
    const float* b1     = (const float*)d_in[3];
    const float* W2     = (const float*)d_in[4];
    const float* b2     = (const float*)d_in[5];
    const float* gate   = (const float*)d_in[6];
    const float* memory = (const float*)d_in[7];
    const int*   topk   = (const int*)d_in[8];
    float* out = (float*)d_out;

    // workspace layout (floats) — ~2.3 MB
    float* partial = (float*)d_ws;                        // B*SCHUNK*H = 524288
    float* q       = partial + (size_t)B * SCHUNK * H;    // B*H        = 32768
    float* hws     = q       + (size_t)B * H;             // B*RH       = 2048
    float* contrib = hws     + (size_t)B * RH;            // B*H        = 32768

    k_partial     <<<dim3(B * (H4 / 256) * SCHUNK), dim3(256), 0, stream>>>(embeds, partial);
    k_mean        <<<dim3(B * H4 / 256),            dim3(256), 0, stream>>>(partial, q);
    k_w1          <<<dim3(RH),                      dim3(256), 0, stream>>>(q, W1, b1, hws);
    k_gate_contrib<<<dim3(B * (H4 / 64)),           dim3(64),  0, stream>>>(hws, W2, b2, gate,
                                                                            memory, topk, contrib);
    k_add         <<<dim3(4096),                    dim3(256), 0, stream>>>(hidden, contrib, out);
}